// Round 4
// baseline (180.299 us; speedup 1.0000x reference)
//
#include <hip/hip_runtime.h>
#include <hip/hip_bf16.h>

#define T_TOKENS 2048
#define DIM 256
#define NLEV 8

using bf16x8 = __attribute__((ext_vector_type(8))) short;
using f32x4  = __attribute__((ext_vector_type(4))) float;

__device__ __forceinline__ unsigned short f2bf(float f) {
    union { float f; unsigned u; } v; v.f = f;
    unsigned r = v.u + 0x7FFFu + ((v.u >> 16) & 1u);   // RNE
    return (unsigned short)(r >> 16);
}

// ---------------- Kernel 1: routing (exact fp32) ----------------
__global__ __launch_bounds__(256) void route_kernel(
    const float* __restrict__ x, const float* __restrict__ w1s,
    const float* __restrict__ b1s,
    float* __restrict__ pw,   // [T][8]
    int*   __restrict__ pc)   // [T] pathcode in [256,511]
{
    int wave = threadIdx.x >> 6;
    int lane = threadIdx.x & 63;
    int t = blockIdx.x * 4 + wave;    // grid = 512 -> t < 2048

    const float4 xv = *reinterpret_cast<const float4*>(x + (size_t)t * DIM + lane * 4);
    int p = 1;
    float keep = 0.0f;
    #pragma unroll
    for (int lvl = 0; lvl < NLEV; ++lvl) {
        int node = p - 1;
        const float4 wv = *reinterpret_cast<const float4*>(w1s + (size_t)node * DIM + lane * 4);
        float s = xv.x * wv.x + xv.y * wv.y + xv.z * wv.z + xv.w * wv.w;
        #pragma unroll
        for (int off = 32; off; off >>= 1) s += __shfl_xor(s, off);
        float score = s + b1s[node];
        float a = fabsf(score);
        float g = a * 0.5f * (1.0f + erff(a * 0.70710678118654752f));  // exact GELU
        if (lane == lvl) keep = g;
        int choice = (score > 0.0f) ? 1 : 0;   // sign(0)->choice 0 matches ref
        p = 2 * p + choice;
    }
    if (lane < NLEV) pw[(size_t)t * NLEV + lane] = keep;
    if (lane == 0) pc[t] = p;
}

// ---------------- Kernel 2: counting sort by pathcode (1 block) ----------------
__global__ __launch_bounds__(256) void sort_kernel(
    const int* __restrict__ pc,
    int* __restrict__ order, int* __restrict__ spc)
{
    __shared__ int hist[256];
    __shared__ int offs[256];
    int tid = threadIdx.x;
    hist[tid] = 0;
    __syncthreads();

    int myPc[8];
    #pragma unroll
    for (int i = 0; i < 8; ++i) {
        int t = tid * 8 + i;
        myPc[i] = pc[t];
        atomicAdd(&hist[myPc[i] - 256], 1);
    }
    __syncthreads();

    if (tid < 64) {
        int lane = tid;
        int v0 = hist[lane * 4 + 0], v1 = hist[lane * 4 + 1];
        int v2 = hist[lane * 4 + 2], v3 = hist[lane * 4 + 3];
        int sum = v0 + v1 + v2 + v3;
        int scan = sum;
        #pragma unroll
        for (int off = 1; off < 64; off <<= 1) {
            int n = __shfl_up(scan, off);
            if (lane >= off) scan += n;
        }
        int excl = scan - sum;
        offs[lane * 4 + 0] = excl;
        offs[lane * 4 + 1] = excl + v0;
        offs[lane * 4 + 2] = excl + v0 + v1;
        offs[lane * 4 + 3] = excl + v0 + v1 + v2;
    }
    __syncthreads();

    #pragma unroll
    for (int i = 0; i < 8; ++i) {
        int t = tid * 8 + i;
        int bin = myPc[i] - 256;
        int pos = atomicAdd(&offs[bin], 1);
        order[pos] = t;
        spc[pos] = myPc[i];
    }
}

// ---------------- Kernel 3: path-weighted output via bf16 MFMA ----------------
// Wave-item = (16 sorted tokens) x (16 cols). grid = 512 blocks x 4 waves.
// Segment list pre-enumerated into LDS; 2-deep software pipeline with two
// 64-float register buffers so next segment's 64 B-loads overlap current
// segment's convert+MFMA. launch_bounds(256,2) unlocks ~256 VGPRs.
__global__ __launch_bounds__(256, 2) void out_kernel(
    const float* __restrict__ x, const float* __restrict__ w2s,
    const float* __restrict__ b2s, const float* __restrict__ pw,
    const int* __restrict__ order, const int* __restrict__ spc,
    float* __restrict__ out)
{
    __shared__ unsigned segbuf[4][80];
    __shared__ float pwlds[16][9];   // padded: bank-conflict-free epilogue reads

    int wv   = threadIdx.x >> 6;
    int lane = threadIdx.x & 63;
    int tileId  = blockIdx.x >> 2;                    // 0..127
    int colBase = ((blockIdx.x & 3) * 4 + wv) * 16;   // 0..240 step 16
    int row = lane & 15;
    int kg  = lane >> 4;                              // 0..3
    int kg4 = kg * 4;
    int kg8 = kg * 8;
    int base = tileId * 16;
    int colIdx = colBase + row;                       // (lane&15) == row

    int tok  = order[base + row];
    int myPc = spc[base + row];

    // stage path weights for this tile: pwlds[r][lvl]
    if (threadIdx.x < 128) {
        int r = threadIdx.x >> 3, l = threadIdx.x & 7;
        pwlds[r][l] = pw[(size_t)order[base + r] * NLEV + l];
    }
    __syncthreads();

    // A fragments: afrag[ks] holds x[tok][ks*32 + kg*8 .. +7] as bf16
    bf16x8 afrag[8];
    #pragma unroll
    for (int ks = 0; ks < 8; ++ks) {
        const float* xp = x + (size_t)tok * DIM + ks * 32 + kg8;
        float4 a0 = *reinterpret_cast<const float4*>(xp);
        float4 a1 = *reinterpret_cast<const float4*>(xp + 4);
        bf16x8 av;
        av[0] = (short)f2bf(a0.x); av[1] = (short)f2bf(a0.y);
        av[2] = (short)f2bf(a0.z); av[3] = (short)f2bf(a0.w);
        av[4] = (short)f2bf(a1.x); av[5] = (short)f2bf(a1.y);
        av[6] = (short)f2bf(a1.z); av[7] = (short)f2bf(a1.w);
        afrag[ks] = av;
    }

    // enumerate segments (all 8 levels) into LDS: pack node|s<<8|e<<12|lvl<<17
    int ns = 0;
    for (int lvl = 0; lvl < NLEV; ++lvl) {
        int key = myPc >> (NLEV - lvl);
        int prevKey = __shfl(key, (lane + 63) & 63);
        bool bnd = (row == 0) || (prevKey != key);
        unsigned long long bm = __ballot(bnd) & 0xFFFFull;
        int s = 0;
        while (s < 16) {
            unsigned long long rest = bm >> (s + 1);
            int e = rest ? (s + (int)__ffsll((long long)rest)) : 16;
            int node = __shfl(key, s) - 1;
            if (lane == 0)
                segbuf[wv][ns] = (unsigned)node | ((unsigned)s << 8) |
                                 ((unsigned)e << 12) | ((unsigned)lvl << 17);
            ns++;
            s = e;
        }
    }

    f32x4 Oacc = {0.f, 0.f, 0.f, 0.f};

    auto LOADB = [&](float (&buf)[64], float &bias, unsigned sd) {
        int node = (int)(sd & 0xFFu);
        const float* w2n = w2s + ((size_t)node << 16) + colIdx;
        #pragma unroll
        for (int ks = 0; ks < 8; ++ks)
            #pragma unroll
            for (int i = 0; i < 8; ++i)
                buf[ks * 8 + i] = w2n[(size_t)(ks * 32 + kg8 + i) * DIM];
        bias = b2s[((size_t)node << 8) + colIdx];
    };

    auto DOMFMA = [&](const float (&buf)[64], float bias, unsigned sd) {
        int s   = (int)((sd >> 8)  & 0xFu);
        int e   = (int)((sd >> 12) & 0x1Fu);
        int lvl = (int)((sd >> 17) & 0x7u);
        f32x4 acc = {0.f, 0.f, 0.f, 0.f};
        #pragma unroll
        for (int ks = 0; ks < 8; ++ks) {
            bf16x8 bv;
            #pragma unroll
            for (int i = 0; i < 8; ++i) bv[i] = (short)f2bf(buf[ks * 8 + i]);
            acc = __builtin_amdgcn_mfma_f32_16x16x32_bf16(afrag[ks], bv, acc, 0, 0, 0);
        }
        #pragma unroll
        for (int j = 0; j < 4; ++j) {
            int r = kg4 + j;
            float w = (r >= s && r < e) ? pwlds[r][lvl] : 0.0f;
            Oacc[j] += w * (acc[j] + bias);
        }
    };

    float bufA[64], bufB[64];
    float biasA, biasB;

    unsigned sdA = segbuf[wv][0];
    LOADB(bufA, biasA, sdA);
    int i = 0;
    for (; i + 2 <= ns; i += 2) {
        unsigned sdB = segbuf[wv][i + 1];
        LOADB(bufB, biasB, sdB);
        DOMFMA(bufA, biasA, sdA);
        if (i + 2 < ns) {
            sdA = segbuf[wv][i + 2];
            LOADB(bufA, biasA, sdA);
        }
        DOMFMA(bufB, biasB, sdB);
    }
    if (i < ns) {
        DOMFMA(bufA, biasA, sdA);   // odd tail: already loaded
    }

    #pragma unroll
    for (int j = 0; j < 4; ++j) {
        int r = kg4 + j;
        int otok = __shfl(tok, r);
        out[(size_t)otok * DIM + colIdx] = Oacc[j];
    }
}

extern "C" void kernel_launch(void* const* d_in, const int* in_sizes, int n_in,
                              void* d_out, int out_size, void* d_ws, size_t ws_size,
                              hipStream_t stream) {
    const float* x   = (const float*)d_in[0];
    const float* w1s = (const float*)d_in[1];
    const float* b1s = (const float*)d_in[2];
    const float* w2s = (const float*)d_in[3];
    const float* b2s = (const float*)d_in[4];
    float* out = (float*)d_out;

    float* pw  = (float*)d_ws;                 // 2048*8 f32
    int* pc    = (int*)(pw + T_TOKENS * NLEV); // 2048
    int* order = pc + T_TOKENS;                // 2048
    int* spc   = order + T_TOKENS;             // 2048

    route_kernel<<<T_TOKENS / 4, 256, 0, stream>>>(x, w1s, b1s, pw, pc);
    sort_kernel<<<1, 256, 0, stream>>>(pc, order, spc);
    out_kernel<<<128 * 4, 256, 0, stream>>>(x, w2s, b2s, pw, order, spc, out);
}

// Round 5
// 52.543 us; speedup vs baseline: 3.4315x; 3.4315x over previous
//
#include <hip/hip_runtime.h>
#include <hip/hip_bf16.h>

#define T_TOKENS 2048
#define DIM 256
#define NLEV 8

using bf16x8 = __attribute__((ext_vector_type(8))) short;
using f32x4  = __attribute__((ext_vector_type(4))) float;

__device__ __forceinline__ unsigned short f2bf(float f) {
    union { float f; unsigned u; } v; v.f = f;
    unsigned r = v.u + 0x7FFFu + ((v.u >> 16) & 1u);   // RNE
    return (unsigned short)(r >> 16);
}

// ---------------- Kernel 1: routing (exact fp32) ----------------
__global__ __launch_bounds__(256) void route_kernel(
    const float* __restrict__ x, const float* __restrict__ w1s,
    const float* __restrict__ b1s,
    float* __restrict__ pw,   // [T][8]
    int*   __restrict__ pc)   // [T] pathcode in [256,511]
{
    int wave = threadIdx.x >> 6;
    int lane = threadIdx.x & 63;
    int t = blockIdx.x * 4 + wave;    // grid = 512 -> t < 2048

    const float4 xv = *reinterpret_cast<const float4*>(x + (size_t)t * DIM + lane * 4);
    int p = 1;
    float keep = 0.0f;
    #pragma unroll
    for (int lvl = 0; lvl < NLEV; ++lvl) {
        int node = p - 1;
        const float4 wv = *reinterpret_cast<const float4*>(w1s + (size_t)node * DIM + lane * 4);
        float s = xv.x * wv.x + xv.y * wv.y + xv.z * wv.z + xv.w * wv.w;
        #pragma unroll
        for (int off = 32; off; off >>= 1) s += __shfl_xor(s, off);
        float score = s + b1s[node];
        float a = fabsf(score);
        float g = a * 0.5f * (1.0f + erff(a * 0.70710678118654752f));  // exact GELU
        if (lane == lvl) keep = g;
        int choice = (score > 0.0f) ? 1 : 0;   // sign(0)->choice 0 matches ref
        p = 2 * p + choice;
    }
    if (lane < NLEV) pw[(size_t)t * NLEV + lane] = keep;
    if (lane == 0) pc[t] = p;
}

// ---------------- Kernel 2: counting sort + unit enumeration (1 block) ----------------
// Units: (node, <=64-token chunk of its contiguous sorted range). <=511 total.
__global__ __launch_bounds__(256) void sort_kernel(
    const int* __restrict__ pc,
    int* __restrict__ order, unsigned* __restrict__ units, int* __restrict__ ucount)
{
    __shared__ int hist[256];
    __shared__ int offs[256];
    __shared__ int cums[257];
    __shared__ int wpart[4];
    int tid = threadIdx.x;
    hist[tid] = 0;
    __syncthreads();

    int myPc[8];
    #pragma unroll
    for (int i = 0; i < 8; ++i) {
        int t = tid * 8 + i;
        myPc[i] = pc[t];
        atomicAdd(&hist[myPc[i] - 256], 1);
    }
    __syncthreads();

    if (tid < 64) {   // wave-0 exclusive scan over 256 bins (4 per lane)
        int lane = tid;
        int v0 = hist[lane * 4 + 0], v1 = hist[lane * 4 + 1];
        int v2 = hist[lane * 4 + 2], v3 = hist[lane * 4 + 3];
        int sum = v0 + v1 + v2 + v3;
        int scan = sum;
        #pragma unroll
        for (int off = 1; off < 64; off <<= 1) {
            int n = __shfl_up(scan, off);
            if (lane >= off) scan += n;
        }
        int excl = scan - sum;
        offs[lane * 4 + 0] = excl;
        offs[lane * 4 + 1] = excl + v0;
        offs[lane * 4 + 2] = excl + v0 + v1;
        offs[lane * 4 + 3] = excl + v0 + v1 + v2;
    }
    __syncthreads();

    cums[tid] = offs[tid];          // snapshot before scatter mutates offs
    if (tid == 0) cums[256] = T_TOKENS;
    __syncthreads();

    #pragma unroll
    for (int i = 0; i < 8; ++i) {
        int t = tid * 8 + i;
        int bin = myPc[i] - 256;
        int pos = atomicAdd(&offs[bin], 1);
        order[pos] = t;
    }

    // ---- unit enumeration: thread tid = node id (0..254) ----
    int nch = 0, s = 0, e = 0, l = 0;
    if (tid < 255) {
        int q = tid + 1;                 // prefix value
        l = 31 - __clz(q);               // level
        int shift = 8 - l;
        int lo = (q << shift) - 256;
        int hi = ((q + 1) << shift) - 256;
        s = cums[lo];
        e = cums[hi];
        nch = (e - s + 63) >> 6;
    }
    int lane = tid & 63, w = tid >> 6;
    int scan = nch;
    #pragma unroll
    for (int off = 1; off < 64; off <<= 1) {
        int n = __shfl_up(scan, off);
        if (lane >= off) scan += n;
    }
    if (lane == 63) wpart[w] = scan;
    __syncthreads();
    int pre = 0;
    for (int k = 0; k < w; ++k) pre += wpart[k];
    int base = pre + scan - nch;
    for (int j = 0; j < nch; ++j) {
        int st = s + j * 64;
        int c = e - st; if (c > 64) c = 64;
        units[base + j] = (unsigned)tid | ((unsigned)l << 8) |
                          ((unsigned)st << 11) | ((unsigned)c << 22);
    }
    if (tid == 255) *ucount = pre + scan;
}

// ---------------- Kernel 3: per-unit dense GEMM, atomicAdd accumulate ----------------
// Block = unit (node, <=64 tokens). 4 waves; wave wv -> cols wv*64..+63.
// A: 64x256 bf16 LDS (swizzled granules); B: 32k x 256c bf16 panels, double-buffered.
__global__ __launch_bounds__(256, 2) void out_kernel(
    const float* __restrict__ x, const float* __restrict__ w2s,
    const float* __restrict__ b2s, const float* __restrict__ pw,
    const int* __restrict__ order, const unsigned* __restrict__ units,
    const int* __restrict__ ucount, float* __restrict__ out)
{
    __shared__ unsigned short As[16384];      // 32 KiB: granule(row,gk) = row*32 + (gk ^ (row&7))
    __shared__ unsigned short Bs[2][8192];    // 2 x 16 KiB: granule(kp,col) = kp*256 + (col ^ ((col>>3)&7))

    int u = blockIdx.x;
    if (u >= *ucount) return;
    unsigned d = units[u];
    int node  = (int)(d & 255u);
    int lvl   = (int)((d >> 8) & 7u);
    int start = (int)((d >> 11) & 2047u);
    int cnt   = (int)((d >> 22) & 127u);

    int tid = threadIdx.x;
    int wv = tid >> 6, lane = tid & 63;
    int l15 = lane & 15, kg = lane >> 4;

    const float* w2n = w2s + ((size_t)node << 16);

    float La[32];
    auto loadB = [&](int p) {
        const float* bp = w2n + (size_t)(p * 32 + wv * 8) * DIM + lane * 4;
        #pragma unroll
        for (int j = 0; j < 8; ++j) {
            float4 v = *reinterpret_cast<const float4*>(bp + (size_t)j * DIM);
            La[j * 4 + 0] = v.x; La[j * 4 + 1] = v.y;
            La[j * 4 + 2] = v.z; La[j * 4 + 3] = v.w;
        }
    };
    auto writeB = [&](unsigned short* bs) {
        #pragma unroll
        for (int q = 0; q < 4; ++q) {
            bf16x8 v;
            #pragma unroll
            for (int j = 0; j < 8; ++j) v[j] = (short)f2bf(La[j * 4 + q]);
            int col = lane * 4 + q;
            int g = wv * 256 + (col ^ ((col >> 3) & 7));
            *reinterpret_cast<bf16x8*>(&bs[g * 8]) = v;
        }
    };

    loadB(0);

    // stage A: thread -> (row = tid>>2, seg = tid&3 covering k 64*seg..+63)
    {
        int r = tid >> 2, seg = tid & 3;
        if (r < cnt) {
            int t = order[start + r];
            const float* xp = x + (size_t)t * DIM + seg * 64;
            #pragma unroll
            for (int g = 0; g < 8; ++g) {
                float4 a0 = *reinterpret_cast<const float4*>(xp + g * 8);
                float4 a1 = *reinterpret_cast<const float4*>(xp + g * 8 + 4);
                bf16x8 v;
                v[0] = (short)f2bf(a0.x); v[1] = (short)f2bf(a0.y);
                v[2] = (short)f2bf(a0.z); v[3] = (short)f2bf(a0.w);
                v[4] = (short)f2bf(a1.x); v[5] = (short)f2bf(a1.y);
                v[6] = (short)f2bf(a1.z); v[7] = (short)f2bf(a1.w);
                int gk = seg * 8 + g;
                int gg = r * 32 + (gk ^ (r & 7));
                *reinterpret_cast<bf16x8*>(&As[gg * 8]) = v;
            }
        }
    }
    writeB(Bs[0]);
    __syncthreads();

    f32x4 acc[4][4];
    #pragma unroll
    for (int m = 0; m < 4; ++m)
        #pragma unroll
        for (int nb = 0; nb < 4; ++nb) acc[m][nb] = (f32x4){0.f, 0.f, 0.f, 0.f};

    for (int p = 0; p < 8; ++p) {
        if (p < 7) loadB(p + 1);
        unsigned short* bs = Bs[p & 1];
        bf16x8 a[4], b[4];
        #pragma unroll
        for (int m = 0; m < 4; ++m) if (m * 16 < cnt) {
            int row = m * 16 + l15;
            int g = row * 32 + ((p * 4 + kg) ^ (row & 7));
            a[m] = *reinterpret_cast<bf16x8*>(&As[g * 8]);
        }
        #pragma unroll
        for (int nb = 0; nb < 4; ++nb) {
            int col = wv * 64 + nb * 16 + l15;
            int g = kg * 256 + (col ^ ((col >> 3) & 7));
            b[nb] = *reinterpret_cast<bf16x8*>(&bs[g * 8]);
        }
        #pragma unroll
        for (int m = 0; m < 4; ++m) if (m * 16 < cnt)
            #pragma unroll
            for (int nb = 0; nb < 4; ++nb)
                acc[m][nb] = __builtin_amdgcn_mfma_f32_16x16x32_bf16(a[m], b[nb], acc[m][nb], 0, 0, 0);
        if (p < 7) writeB(Bs[(p + 1) & 1]);
        __syncthreads();
    }

    // epilogue: out[tok][col] += pw[tok][lvl] * (acc + bias)
    float bias[4];
    #pragma unroll
    for (int nb = 0; nb < 4; ++nb)
        bias[nb] = b2s[((size_t)node << 8) + wv * 64 + nb * 16 + l15];

    #pragma unroll
    for (int m = 0; m < 4; ++m) if (m * 16 < cnt) {
        #pragma unroll
        for (int j = 0; j < 4; ++j) {
            int r = m * 16 + kg * 4 + j;
            if (r < cnt) {
                int t = order[start + r];
                float w = pw[(size_t)t * NLEV + lvl];
                #pragma unroll
                for (int nb = 0; nb < 4; ++nb) {
                    float val = w * (acc[m][nb][j] + bias[nb]);
                    atomicAdd(&out[(size_t)t * DIM + wv * 64 + nb * 16 + l15], val);
                }
            }
        }
    }
}

extern "C" void kernel_launch(void* const* d_in, const int* in_sizes, int n_in,
                              void* d_out, int out_size, void* d_ws, size_t ws_size,
                              hipStream_t stream) {
    const float* x   = (const float*)d_in[0];
    const float* w1s = (const float*)d_in[1];
    const float* b1s = (const float*)d_in[2];
    const float* w2s = (const float*)d_in[3];
    const float* b2s = (const float*)d_in[4];
    float* out = (float*)d_out;

    float* pw       = (float*)d_ws;                    // 2048*8 f32
    int* pc         = (int*)(pw + T_TOKENS * NLEV);    // 2048
    int* order      = pc + T_TOKENS;                   // 2048
    unsigned* units = (unsigned*)(order + T_TOKENS);   // 512
    int* ucount     = (int*)(units + 512);             // 1

    hipMemsetAsync(d_out, 0, (size_t)out_size * sizeof(float), stream);
    route_kernel<<<T_TOKENS / 4, 256, 0, stream>>>(x, w1s, b1s, pw, pc);
    sort_kernel<<<1, 256, 0, stream>>>(pc, order, units, ucount);
    out_kernel<<<512, 256, 0, stream>>>(x, w2s, b2s, pw, order, units, ucount, out);
}

// Round 6
// 52.454 us; speedup vs baseline: 3.4373x; 1.0017x over previous
//
#include <hip/hip_runtime.h>
#include <hip/hip_bf16.h>

#define T_TOKENS 2048
#define DIM 256
#define NLEV 8

using bf16x8 = __attribute__((ext_vector_type(8))) short;
using f32x4  = __attribute__((ext_vector_type(4))) float;

__device__ __forceinline__ unsigned short f2bf(float f) {
    union { float f; unsigned u; } v; v.f = f;
    unsigned r = v.u + 0x7FFFu + ((v.u >> 16) & 1u);   // RNE
    return (unsigned short)(r >> 16);
}

// ---------------- Kernel 1: routing (exact fp32) ----------------
__global__ __launch_bounds__(256) void route_kernel(
    const float* __restrict__ x, const float* __restrict__ w1s,
    const float* __restrict__ b1s,
    float* __restrict__ pw,   // [T][8]
    int*   __restrict__ pc)   // [T] pathcode in [256,511]
{
    int wave = threadIdx.x >> 6;
    int lane = threadIdx.x & 63;
    int t = blockIdx.x * 4 + wave;    // grid = 512 -> t < 2048

    const float4 xv = *reinterpret_cast<const float4*>(x + (size_t)t * DIM + lane * 4);
    int p = 1;
    float keep = 0.0f;
    #pragma unroll
    for (int lvl = 0; lvl < NLEV; ++lvl) {
        int node = p - 1;
        const float4 wv = *reinterpret_cast<const float4*>(w1s + (size_t)node * DIM + lane * 4);
        float s = xv.x * wv.x + xv.y * wv.y + xv.z * wv.z + xv.w * wv.w;
        #pragma unroll
        for (int off = 32; off; off >>= 1) s += __shfl_xor(s, off);
        float score = s + b1s[node];
        float a = fabsf(score);
        float g = a * 0.5f * (1.0f + erff(a * 0.70710678118654752f));  // exact GELU
        if (lane == lvl) keep = g;
        int choice = (score > 0.0f) ? 1 : 0;   // sign(0)->choice 0 matches ref
        p = 2 * p + choice;
    }
    if (lane < NLEV) pw[(size_t)t * NLEV + lane] = keep;
    if (lane == 0) pc[t] = p;
}

// ---------------- Kernel 2: counting sort + unit enumeration (1 block) ----------------
__global__ __launch_bounds__(256) void sort_kernel(
    const int* __restrict__ pc,
    int* __restrict__ order, unsigned* __restrict__ units, int* __restrict__ ucount)
{
    __shared__ int hist[256];
    __shared__ int offs[256];
    __shared__ int cums[257];
    __shared__ int wpart[4];
    int tid = threadIdx.x;
    hist[tid] = 0;
    __syncthreads();

    int myPc[8];
    #pragma unroll
    for (int i = 0; i < 8; ++i) {
        int t = tid * 8 + i;
        myPc[i] = pc[t];
        atomicAdd(&hist[myPc[i] - 256], 1);
    }
    __syncthreads();

    if (tid < 64) {
        int lane = tid;
        int v0 = hist[lane * 4 + 0], v1 = hist[lane * 4 + 1];
        int v2 = hist[lane * 4 + 2], v3 = hist[lane * 4 + 3];
        int sum = v0 + v1 + v2 + v3;
        int scan = sum;
        #pragma unroll
        for (int off = 1; off < 64; off <<= 1) {
            int n = __shfl_up(scan, off);
            if (lane >= off) scan += n;
        }
        int excl = scan - sum;
        offs[lane * 4 + 0] = excl;
        offs[lane * 4 + 1] = excl + v0;
        offs[lane * 4 + 2] = excl + v0 + v1;
        offs[lane * 4 + 3] = excl + v0 + v1 + v2;
    }
    __syncthreads();

    cums[tid] = offs[tid];
    if (tid == 0) cums[256] = T_TOKENS;
    __syncthreads();

    #pragma unroll
    for (int i = 0; i < 8; ++i) {
        int t = tid * 8 + i;
        int bin = myPc[i] - 256;
        int pos = atomicAdd(&offs[bin], 1);
        order[pos] = t;
    }

    int nch = 0, s = 0, e = 0, l = 0;
    if (tid < 255) {
        int q = tid + 1;
        l = 31 - __clz(q);
        int shift = 8 - l;
        int lo = (q << shift) - 256;
        int hi = ((q + 1) << shift) - 256;
        s = cums[lo];
        e = cums[hi];
        nch = (e - s + 63) >> 6;
    }
    int lane = tid & 63, w = tid >> 6;
    int scan = nch;
    #pragma unroll
    for (int off = 1; off < 64; off <<= 1) {
        int n = __shfl_up(scan, off);
        if (lane >= off) scan += n;
    }
    if (lane == 63) wpart[w] = scan;
    __syncthreads();
    int pre = 0;
    for (int k = 0; k < w; ++k) pre += wpart[k];
    int base = pre + scan - nch;
    for (int j = 0; j < nch; ++j) {
        int st = s + j * 64;
        int c = e - st; if (c > 64) c = 64;
        units[base + j] = (unsigned)tid | ((unsigned)l << 8) |
                          ((unsigned)st << 11) | ((unsigned)c << 22);
    }
    if (tid == 255) *ucount = pre + scan;
}

// ---------------- Kernel 3: per-unit col-split GEMM, atomicAdd accumulate ----------------
// Block = (unit, col-half). 4 waves; wave wv covers cols ch*128 + wv*32 .. +31.
// A: 64x256 bf16 (32 KiB, swizzled). B: 32k x 128c bf16 panels, dbuf (2 x 8 KiB).
// LDS 48 KiB -> 3 blocks/CU. B prefetch 2 panels deep via La0/La1 registers.
__global__ __launch_bounds__(256, 3) void out_kernel(
    const float* __restrict__ x, const float* __restrict__ w2s,
    const float* __restrict__ b2s, const float* __restrict__ pw,
    const int* __restrict__ order, const unsigned* __restrict__ units,
    const int* __restrict__ ucount, float* __restrict__ out)
{
    __shared__ unsigned short As[16384];     // granule(row,gk) = row*32 + (gk ^ (row&7))
    __shared__ unsigned short Bs[2][4096];   // granule g = ko*128+col; sidx = g ^ ((g>>3)&7)

    int u = blockIdx.x >> 1;
    int ch = blockIdx.x & 1;
    if (u >= *ucount) return;
    unsigned d = units[u];
    int node  = (int)(d & 255u);
    int lvl   = (int)((d >> 8) & 7u);
    int start = (int)((d >> 11) & 2047u);
    int cnt   = (int)((d >> 22) & 127u);

    int tid = threadIdx.x;
    int wv = tid >> 6, lane = tid & 63;
    int l15 = lane & 15, kg = lane >> 4;

    const float* w2n = w2s + ((size_t)node << 16) + ch * 128;

    float2 La0[8], La1[8];
    auto loadB = [&](int p, float2 (&La)[8]) {
        const float* bp = w2n + (size_t)(p * 32 + wv * 8) * DIM + lane * 2;
        #pragma unroll
        for (int j = 0; j < 8; ++j)
            La[j] = *reinterpret_cast<const float2*>(bp + (size_t)j * DIM);
    };
    auto writeB = [&](unsigned short* bs, const float2 (&La)[8]) {
        bf16x8 v0, v1;
        #pragma unroll
        for (int j = 0; j < 8; ++j) {
            v0[j] = (short)f2bf(La[j].x);
            v1[j] = (short)f2bf(La[j].y);
        }
        int g0 = wv * 128 + lane * 2;
        int g1 = g0 + 1;
        *reinterpret_cast<bf16x8*>(&bs[(g0 ^ ((g0 >> 3) & 7)) * 8]) = v0;
        *reinterpret_cast<bf16x8*>(&bs[(g1 ^ ((g1 >> 3) & 7)) * 8]) = v1;
    };

    loadB(0, La0);
    loadB(1, La1);

    // stage A: thread -> (row = tid>>2, seg = tid&3 covering k 64*seg..+63)
    {
        int r = tid >> 2, seg = tid & 3;
        if (r < cnt) {
            int t = order[start + r];
            const float* xp = x + (size_t)t * DIM + seg * 64;
            #pragma unroll
            for (int g = 0; g < 8; ++g) {
                float4 a0 = *reinterpret_cast<const float4*>(xp + g * 8);
                float4 a1 = *reinterpret_cast<const float4*>(xp + g * 8 + 4);
                bf16x8 v;
                v[0] = (short)f2bf(a0.x); v[1] = (short)f2bf(a0.y);
                v[2] = (short)f2bf(a0.z); v[3] = (short)f2bf(a0.w);
                v[4] = (short)f2bf(a1.x); v[5] = (short)f2bf(a1.y);
                v[6] = (short)f2bf(a1.z); v[7] = (short)f2bf(a1.w);
                int gk = seg * 8 + g;
                int gg = r * 32 + (gk ^ (r & 7));
                *reinterpret_cast<bf16x8*>(&As[gg * 8]) = v;
            }
        }
    }
    writeB(Bs[0], La0);
    __syncthreads();

    f32x4 acc[4][2];
    #pragma unroll
    for (int m = 0; m < 4; ++m)
        #pragma unroll
        for (int nb = 0; nb < 2; ++nb) acc[m][nb] = (f32x4){0.f, 0.f, 0.f, 0.f};

    #pragma unroll
    for (int p = 0; p < 8; ++p) {
        if (p < 6) {
            if (p & 1) loadB(p + 2, La1); else loadB(p + 2, La0);
        }
        unsigned short* bs = Bs[p & 1];
        bf16x8 a[4], b[2];
        #pragma unroll
        for (int nb = 0; nb < 2; ++nb) {
            int g = kg * 128 + wv * 32 + nb * 16 + l15;
            b[nb] = *reinterpret_cast<bf16x8*>(&bs[(g ^ ((g >> 3) & 7)) * 8]);
        }
        #pragma unroll
        for (int m = 0; m < 4; ++m) if (m * 16 < cnt) {
            int row = m * 16 + l15;
            int g = row * 32 + ((p * 4 + kg) ^ (row & 7));
            a[m] = *reinterpret_cast<bf16x8*>(&As[g * 8]);
        }
        #pragma unroll
        for (int m = 0; m < 4; ++m) if (m * 16 < cnt)
            #pragma unroll
            for (int nb = 0; nb < 2; ++nb)
                acc[m][nb] = __builtin_amdgcn_mfma_f32_16x16x32_bf16(a[m], b[nb], acc[m][nb], 0, 0, 0);
        if (p < 7) {
            if (p & 1) writeB(Bs[(p + 1) & 1], La0); else writeB(Bs[(p + 1) & 1], La1);
        }
        __syncthreads();
    }

    // epilogue: out[tok][col] += pw[tok][lvl] * (acc + bias)
    float bias[2];
    #pragma unroll
    for (int nb = 0; nb < 2; ++nb)
        bias[nb] = b2s[((size_t)node << 8) + ch * 128 + wv * 32 + nb * 16 + l15];

    #pragma unroll
    for (int m = 0; m < 4; ++m) if (m * 16 < cnt) {
        #pragma unroll
        for (int j = 0; j < 4; ++j) {
            int r = m * 16 + kg * 4 + j;
            if (r < cnt) {
                int t = order[start + r];
                float w = pw[(size_t)t * NLEV + lvl];
                #pragma unroll
                for (int nb = 0; nb < 2; ++nb) {
                    float val = w * (acc[m][nb][j] + bias[nb]);
                    atomicAdd(&out[(size_t)t * DIM + ch * 128 + wv * 32 + nb * 16 + l15], val);
                }
            }
        }
    }
}

extern "C" void kernel_launch(void* const* d_in, const int* in_sizes, int n_in,
                              void* d_out, int out_size, void* d_ws, size_t ws_size,
                              hipStream_t stream) {
    const float* x   = (const float*)d_in[0];
    const float* w1s = (const float*)d_in[1];
    const float* b1s = (const float*)d_in[2];
    const float* w2s = (const float*)d_in[3];
    const float* b2s = (const float*)d_in[4];
    float* out = (float*)d_out;

    float* pw       = (float*)d_ws;                    // 2048*8 f32
    int* pc         = (int*)(pw + T_TOKENS * NLEV);    // 2048
    int* order      = pc + T_TOKENS;                   // 2048
    unsigned* units = (unsigned*)(order + T_TOKENS);   // 512
    int* ucount     = (int*)(units + 512);             // 1

    hipMemsetAsync(d_out, 0, (size_t)out_size * sizeof(float), stream);
    route_kernel<<<T_TOKENS / 4, 256, 0, stream>>>(x, w1s, b1s, pw, pc);
    sort_kernel<<<1, 256, 0, stream>>>(pc, order, units, ucount);
    out_kernel<<<1024, 256, 0, stream>>>(x, w2s, b2s, pw, order, units, ucount, out);
}

// Round 7
// 46.195 us; speedup vs baseline: 3.9030x; 1.1355x over previous
//
#include <hip/hip_runtime.h>
#include <hip/hip_bf16.h>

#define T_TOKENS 2048
#define DIM 256
#define NLEV 8

using bf16x8 = __attribute__((ext_vector_type(8))) short;
using f32x4  = __attribute__((ext_vector_type(4))) float;

__device__ __forceinline__ unsigned short f2bf(float f) {
    union { float f; unsigned u; } v; v.f = f;
    unsigned r = v.u + 0x7FFFu + ((v.u >> 16) & 1u);   // RNE
    return (unsigned short)(r >> 16);
}

// ---------------- Kernel 1: routing (exact fp32) ----------------
__global__ __launch_bounds__(256) void route_kernel(
    const float* __restrict__ x, const float* __restrict__ w1s,
    const float* __restrict__ b1s,
    float* __restrict__ pw,   // [T][8]
    int*   __restrict__ pc)   // [T] pathcode in [256,511]
{
    int wave = threadIdx.x >> 6;
    int lane = threadIdx.x & 63;
    int t = blockIdx.x * 4 + wave;    // grid = 512 -> t < 2048

    const float4 xv = *reinterpret_cast<const float4*>(x + (size_t)t * DIM + lane * 4);
    int p = 1;
    float keep = 0.0f;
    #pragma unroll
    for (int lvl = 0; lvl < NLEV; ++lvl) {
        int node = p - 1;
        const float4 wv = *reinterpret_cast<const float4*>(w1s + (size_t)node * DIM + lane * 4);
        float s = xv.x * wv.x + xv.y * wv.y + xv.z * wv.z + xv.w * wv.w;
        #pragma unroll
        for (int off = 32; off; off >>= 1) s += __shfl_xor(s, off);
        float score = s + b1s[node];
        float a = fabsf(score);
        float g = a * 0.5f * (1.0f + erff(a * 0.70710678118654752f));  // exact GELU
        if (lane == lvl) keep = g;
        int choice = (score > 0.0f) ? 1 : 0;   // sign(0)->choice 0 matches ref
        p = 2 * p + choice;
    }
    if (lane < NLEV) pw[(size_t)t * NLEV + lane] = keep;
    if (lane == 0) pc[t] = p;
}

// ---------------- Kernel 2: counting sort + unit enumeration (1 block) ----------------
__global__ __launch_bounds__(256) void sort_kernel(
    const int* __restrict__ pc,
    int* __restrict__ order, unsigned* __restrict__ units, int* __restrict__ ucount)
{
    __shared__ int hist[256];
    __shared__ int offs[256];
    __shared__ int cums[257];
    __shared__ int wpart[4];
    int tid = threadIdx.x;
    hist[tid] = 0;
    __syncthreads();

    int myPc[8];
    #pragma unroll
    for (int i = 0; i < 8; ++i) {
        int t = tid * 8 + i;
        myPc[i] = pc[t];
        atomicAdd(&hist[myPc[i] - 256], 1);
    }
    __syncthreads();

    if (tid < 64) {
        int lane = tid;
        int v0 = hist[lane * 4 + 0], v1 = hist[lane * 4 + 1];
        int v2 = hist[lane * 4 + 2], v3 = hist[lane * 4 + 3];
        int sum = v0 + v1 + v2 + v3;
        int scan = sum;
        #pragma unroll
        for (int off = 1; off < 64; off <<= 1) {
            int n = __shfl_up(scan, off);
            if (lane >= off) scan += n;
        }
        int excl = scan - sum;
        offs[lane * 4 + 0] = excl;
        offs[lane * 4 + 1] = excl + v0;
        offs[lane * 4 + 2] = excl + v0 + v1;
        offs[lane * 4 + 3] = excl + v0 + v1 + v2;
    }
    __syncthreads();

    cums[tid] = offs[tid];
    if (tid == 0) cums[256] = T_TOKENS;
    __syncthreads();

    #pragma unroll
    for (int i = 0; i < 8; ++i) {
        int t = tid * 8 + i;
        int bin = myPc[i] - 256;
        int pos = atomicAdd(&offs[bin], 1);
        order[pos] = t;
    }

    int nch = 0, s = 0, e = 0, l = 0;
    if (tid < 255) {
        int q = tid + 1;
        l = 31 - __clz(q);
        int shift = 8 - l;
        int lo = (q << shift) - 256;
        int hi = ((q + 1) << shift) - 256;
        s = cums[lo];
        e = cums[hi];
        nch = (e - s + 63) >> 6;
    }
    int lane = tid & 63, w = tid >> 6;
    int scan = nch;
    #pragma unroll
    for (int off = 1; off < 64; off <<= 1) {
        int n = __shfl_up(scan, off);
        if (lane >= off) scan += n;
    }
    if (lane == 63) wpart[w] = scan;
    __syncthreads();
    int pre = 0;
    for (int k = 0; k < w; ++k) pre += wpart[k];
    int base = pre + scan - nch;
    for (int j = 0; j < nch; ++j) {
        int st = s + j * 64;
        int c = e - st; if (c > 64) c = 64;
        units[base + j] = (unsigned)tid | ((unsigned)l << 8) |
                          ((unsigned)st << 11) | ((unsigned)c << 22);
    }
    if (tid == 255) *ucount = pre + scan;
}

// ---------------- Kernel 3: per-unit col-split GEMM, plain stores to per-level buf ----------------
// Block = (unit, col-half). 4 waves; wave wv covers cols ch*128 + wv*32 .. +31.
// A: 64x256 bf16 (32 KiB, swizzled). B: 32k x 128c bf16 panels, dbuf (2 x 8 KiB).
// LDS 48 KiB -> 3 blocks/CU. Each block writes disjoint [lvl][token][col] cells:
// no atomics, no races (token in exactly one unit per level; col-halves disjoint).
__global__ __launch_bounds__(256, 3) void out_kernel(
    const float* __restrict__ x, const float* __restrict__ w2s,
    const float* __restrict__ b2s, const float* __restrict__ pw,
    const int* __restrict__ order, const unsigned* __restrict__ units,
    const int* __restrict__ ucount, float* __restrict__ lvlbuf)
{
    __shared__ unsigned short As[16384];     // granule(row,gk) = row*32 + (gk ^ (row&7))
    __shared__ unsigned short Bs[2][4096];   // granule g = ko*128+col; sidx = g ^ ((g>>3)&7)

    int u = blockIdx.x >> 1;
    int ch = blockIdx.x & 1;
    if (u >= *ucount) return;
    unsigned d = units[u];
    int node  = (int)(d & 255u);
    int lvl   = (int)((d >> 8) & 7u);
    int start = (int)((d >> 11) & 2047u);
    int cnt   = (int)((d >> 22) & 127u);

    int tid = threadIdx.x;
    int wv = tid >> 6, lane = tid & 63;
    int l15 = lane & 15, kg = lane >> 4;

    const float* w2n = w2s + ((size_t)node << 16) + ch * 128;

    float2 La0[8], La1[8];
    auto loadB = [&](int p, float2 (&La)[8]) {
        const float* bp = w2n + (size_t)(p * 32 + wv * 8) * DIM + lane * 2;
        #pragma unroll
        for (int j = 0; j < 8; ++j)
            La[j] = *reinterpret_cast<const float2*>(bp + (size_t)j * DIM);
    };
    auto writeB = [&](unsigned short* bs, const float2 (&La)[8]) {
        bf16x8 v0, v1;
        #pragma unroll
        for (int j = 0; j < 8; ++j) {
            v0[j] = (short)f2bf(La[j].x);
            v1[j] = (short)f2bf(La[j].y);
        }
        int g0 = wv * 128 + lane * 2;
        int g1 = g0 + 1;
        *reinterpret_cast<bf16x8*>(&bs[(g0 ^ ((g0 >> 3) & 7)) * 8]) = v0;
        *reinterpret_cast<bf16x8*>(&bs[(g1 ^ ((g1 >> 3) & 7)) * 8]) = v1;
    };

    loadB(0, La0);
    loadB(1, La1);

    // stage A: thread -> (row = tid>>2, seg = tid&3 covering k 64*seg..+63)
    {
        int r = tid >> 2, seg = tid & 3;
        if (r < cnt) {
            int t = order[start + r];
            const float* xp = x + (size_t)t * DIM + seg * 64;
            #pragma unroll
            for (int g = 0; g < 8; ++g) {
                float4 a0 = *reinterpret_cast<const float4*>(xp + g * 8);
                float4 a1 = *reinterpret_cast<const float4*>(xp + g * 8 + 4);
                bf16x8 v;
                v[0] = (short)f2bf(a0.x); v[1] = (short)f2bf(a0.y);
                v[2] = (short)f2bf(a0.z); v[3] = (short)f2bf(a0.w);
                v[4] = (short)f2bf(a1.x); v[5] = (short)f2bf(a1.y);
                v[6] = (short)f2bf(a1.z); v[7] = (short)f2bf(a1.w);
                int gk = seg * 8 + g;
                int gg = r * 32 + (gk ^ (r & 7));
                *reinterpret_cast<bf16x8*>(&As[gg * 8]) = v;
            }
        }
    }
    writeB(Bs[0], La0);
    __syncthreads();

    f32x4 acc[4][2];
    #pragma unroll
    for (int m = 0; m < 4; ++m)
        #pragma unroll
        for (int nb = 0; nb < 2; ++nb) acc[m][nb] = (f32x4){0.f, 0.f, 0.f, 0.f};

    #pragma unroll
    for (int p = 0; p < 8; ++p) {
        if (p < 6) {
            if (p & 1) loadB(p + 2, La1); else loadB(p + 2, La0);
        }
        unsigned short* bs = Bs[p & 1];
        bf16x8 a[4], b[2];
        #pragma unroll
        for (int nb = 0; nb < 2; ++nb) {
            int g = kg * 128 + wv * 32 + nb * 16 + l15;
            b[nb] = *reinterpret_cast<bf16x8*>(&bs[(g ^ ((g >> 3) & 7)) * 8]);
        }
        #pragma unroll
        for (int m = 0; m < 4; ++m) if (m * 16 < cnt) {
            int row = m * 16 + l15;
            int g = row * 32 + ((p * 4 + kg) ^ (row & 7));
            a[m] = *reinterpret_cast<bf16x8*>(&As[g * 8]);
        }
        #pragma unroll
        for (int m = 0; m < 4; ++m) if (m * 16 < cnt)
            #pragma unroll
            for (int nb = 0; nb < 2; ++nb)
                acc[m][nb] = __builtin_amdgcn_mfma_f32_16x16x32_bf16(a[m], b[nb], acc[m][nb], 0, 0, 0);
        if (p < 7) {
            if (p & 1) writeB(Bs[(p + 1) & 1], La0); else writeB(Bs[(p + 1) & 1], La1);
        }
        __syncthreads();
    }

    // epilogue: lvlbuf[lvl][tok][col] = pw[tok][lvl] * (acc + bias)  (plain store)
    float bias[2];
    #pragma unroll
    for (int nb = 0; nb < 2; ++nb)
        bias[nb] = b2s[((size_t)node << 8) + ch * 128 + wv * 32 + nb * 16 + l15];

    float* dst = lvlbuf + ((size_t)lvl << 19);   // 2048*256 = 1<<19 per level

    #pragma unroll
    for (int m = 0; m < 4; ++m) if (m * 16 < cnt) {
        #pragma unroll
        for (int j = 0; j < 4; ++j) {
            int r = m * 16 + kg * 4 + j;
            if (r < cnt) {
                int t = order[start + r];
                float w = pw[(size_t)t * NLEV + lvl];
                #pragma unroll
                for (int nb = 0; nb < 2; ++nb) {
                    float val = w * (acc[m][nb][j] + bias[nb]);
                    dst[(size_t)t * DIM + ch * 128 + wv * 32 + nb * 16 + l15] = val;
                }
            }
        }
    }
}

// ---------------- Kernel 4: reduce 8 level-buffers -> out ----------------
__global__ __launch_bounds__(256) void reduce_kernel(
    const float* __restrict__ lvlbuf, float* __restrict__ out)
{
    int idx = blockIdx.x * 256 + threadIdx.x;          // float4 index, < 131072
    const float4* lb = reinterpret_cast<const float4*>(lvlbuf);
    float4 s = lb[idx];
    #pragma unroll
    for (int l = 1; l < NLEV; ++l) {
        float4 v = lb[(size_t)l * 131072 + idx];
        s.x += v.x; s.y += v.y; s.z += v.z; s.w += v.w;
    }
    reinterpret_cast<float4*>(out)[idx] = s;
}

extern "C" void kernel_launch(void* const* d_in, const int* in_sizes, int n_in,
                              void* d_out, int out_size, void* d_ws, size_t ws_size,
                              hipStream_t stream) {
    const float* x   = (const float*)d_in[0];
    const float* w1s = (const float*)d_in[1];
    const float* b1s = (const float*)d_in[2];
    const float* w2s = (const float*)d_in[3];
    const float* b2s = (const float*)d_in[4];
    float* out = (float*)d_out;

    float* pw       = (float*)d_ws;                    // 2048*8 f32   (64 KB)
    int* pc         = (int*)(pw + T_TOKENS * NLEV);    // 2048
    int* order      = pc + T_TOKENS;                   // 2048
    unsigned* units = (unsigned*)(order + T_TOKENS);   // 512
    int* ucount     = (int*)(units + 512);             // 1
    float* lvlbuf   = (float*)((char*)d_ws + (1 << 20));  // 8 * 2048 * 256 f32 = 16 MB

    route_kernel<<<T_TOKENS / 4, 256, 0, stream>>>(x, w1s, b1s, pw, pc);
    sort_kernel<<<1, 256, 0, stream>>>(pc, order, units, ucount);
    out_kernel<<<1024, 256, 0, stream>>>(x, w2s, b2s, pw, order, units, ucount, lvlbuf);
    reduce_kernel<<<512, 256, 0, stream>>>(lvlbuf, out);
}